// Round 1
// baseline (3899.669 us; speedup 1.0000x reference)
//
#include <hip/hip_runtime.h>

#define B_ 16
#define S_ 4096
#define D_ 256
#define H_ 256

typedef _Float16 h2 __attribute__((ext_vector_type(2)));
typedef _Float16 h8 __attribute__((ext_vector_type(8)));
typedef float f4 __attribute__((ext_vector_type(4)));

#if defined(__has_builtin)
#if __has_builtin(__builtin_amdgcn_fdot2)
#define HAVE_FDOT2 1
#endif
#if __has_builtin(__builtin_amdgcn_exp2f)
#define HAVE_EXP2 1
#endif
#endif

static __device__ __forceinline__ float fdot2f(h2 a, h2 b, float c) {
#ifdef HAVE_FDOT2
    return __builtin_amdgcn_fdot2(a, b, c, false);
#else
    float d = c;
    asm("v_dot2_f32_f16 %0, %1, %2, %0" : "+v"(d) : "v"(a), "v"(b));
    return d;
#endif
}

static __device__ __forceinline__ float exp2_fast(float x) {
#ifdef HAVE_EXP2
    return __builtin_amdgcn_exp2f(x);
#else
    return exp2f(x);
#endif
}

// Kernel 1: xp[r][h] = sum_d x[r][d] * Wx[d][h] + bias[h]
// r = b*S + s (65536 rows). Written straight into d_out (scan overwrites in place).
// fp32 VALU GEMM: block = 256 threads, BM = 32 rows, BN = 256 (full H).
__global__ __launch_bounds__(256) void xproj_kernel(
    const float* __restrict__ x, const float* __restrict__ Wx,
    const float* __restrict__ bias, float* __restrict__ out)
{
    __shared__ float xs[32 * 256];   // 32 KB staged x tile
    const int tid = threadIdx.x;
    const long long row0 = (long long)blockIdx.x * 32;

    // stage 32 rows (coalesced float4: each instr covers 1KB contiguous)
    {
        const f4* __restrict__ xg = (const f4*)(x + row0 * D_);
        f4* xsv = (f4*)xs;
        #pragma unroll
        for (int k = 0; k < 8; ++k)
            xsv[tid + k * 256] = xg[tid + k * 256];
    }
    __syncthreads();

    const int j = tid;               // output column h
    float acc[32];
    const float bj = bias[j];
    #pragma unroll
    for (int r = 0; r < 32; ++r) acc[r] = bj;

    for (int d4 = 0; d4 < D_ / 4; ++d4) {
        // 4 weight rows, coalesced across j
        const float w0 = Wx[(d4 * 4 + 0) * H_ + j];
        const float w1 = Wx[(d4 * 4 + 1) * H_ + j];
        const float w2 = Wx[(d4 * 4 + 2) * H_ + j];
        const float w3 = Wx[(d4 * 4 + 3) * H_ + j];
        #pragma unroll
        for (int r = 0; r < 32; ++r) {
            f4 xv = *(const f4*)&xs[r * 256 + d4 * 4];  // LDS broadcast (same addr per wave)
            acc[r] = fmaf(xv.x, w0, acc[r]);
            acc[r] = fmaf(xv.y, w1, acc[r]);
            acc[r] = fmaf(xv.z, w2, acc[r]);
            acc[r] = fmaf(xv.w, w3, acc[r]);
        }
    }
    #pragma unroll
    for (int r = 0; r < 32; ++r)
        out[(row0 + r) * H_ + j] = acc[r];
}

// Kernel 2: sequential scan. One block per batch (16 blocks, 256 threads).
// Thread j owns output column j: Wh[:,j] lives in 128 packed v2f16 VGPRs.
// h broadcast via double-buffered LDS fp16 buffer; ONE barrier per step.
// Reads xp from d_out and overwrites the same slot with h_t (read-once).
__global__ __launch_bounds__(256, 1) void scan_kernel(
    const float* __restrict__ Wh, const float* __restrict__ state0,
    float* __restrict__ out)
{
    __shared__ __align__(16) _Float16 hbuf[2][H_];
    const int j = threadIdx.x;
    const int b = blockIdx.x;

    // Wh column j -> fp16 pairs in registers (fully unrolled: static reg indexing)
    h2 w[128];
    #pragma unroll
    for (int i = 0; i < 128; ++i) {
        float wa = Wh[(2 * i)     * H_ + j];
        float wb = Wh[(2 * i + 1) * H_ + j];
        h2 p;
        p[0] = (_Float16)wa;
        p[1] = (_Float16)wb;
        w[i] = p;
    }

    hbuf[0][j] = (_Float16)state0[b * H_ + j];

    float* __restrict__ outb = out + (long long)b * S_ * H_;

    // xp prefetch ring (distance 3 covers L2/L3 latency under the dot compute)
    float xp0 = outb[(long long)0 * H_ + j];
    float xp1 = outb[(long long)1 * H_ + j];
    float xp2 = outb[(long long)2 * H_ + j];
    __syncthreads();

    for (int t = 0; t < S_; ++t) {
        const int p = t & 1;
        float a0 = 0.f, a1 = 0.f, a2 = 0.f, a3 = 0.f;
        #pragma unroll
        for (int c = 0; c < 32; ++c) {
            h8 hv = *(const h8*)&hbuf[p][c * 8];   // 16B LDS broadcast read
            union { h8 v; h2 q[4]; } u;
            u.v = hv;
            a0 = fdot2f(u.q[0], w[c * 4 + 0], a0);
            a1 = fdot2f(u.q[1], w[c * 4 + 1], a1);
            a2 = fdot2f(u.q[2], w[c * 4 + 2], a2);
            a3 = fdot2f(u.q[3], w[c * 4 + 3], a3);
        }
        float pre = ((a0 + a1) + (a2 + a3)) + xp0;
        // tanh(x) = 1 - 2/(exp2(x * 2*log2(e)) + 1); saturates correctly at +-inf
        float e = exp2_fast(pre * 2.8853900817779268f);
        float hn = 1.f - 2.f / (e + 1.f);

        outb[(long long)t * H_ + j] = hn;          // overwrite xp slot with output
        hbuf[p ^ 1][j] = (_Float16)hn;             // publish h for next step

        xp0 = xp1; xp1 = xp2;
        xp2 = (t + 3 < S_) ? outb[(long long)(t + 3) * H_ + j] : 0.f;
        __syncthreads();
    }
}

extern "C" void kernel_launch(void* const* d_in, const int* in_sizes, int n_in,
                              void* d_out, int out_size, void* d_ws, size_t ws_size,
                              hipStream_t stream) {
    const float* x  = (const float*)d_in[0];   // [B,S,D]
    const float* s0 = (const float*)d_in[1];   // [B,H]
    const float* Wx = (const float*)d_in[2];   // [D,H]
    const float* Wh = (const float*)d_in[3];   // [H,H]
    const float* bv = (const float*)d_in[4];   // [H]
    float* out = (float*)d_out;                // [B,S,H]

    xproj_kernel<<<dim3((B_ * S_) / 32), dim3(256), 0, stream>>>(x, Wx, bv, out);
    scan_kernel<<<dim3(B_), dim3(256), 0, stream>>>(Wh, s0, out);
}